// Round 7
// baseline (1581.533 us; speedup 1.0000x reference)
//
#include <hip/hip_runtime.h>
#include <stdint.h>

#define N_PTS 262144
#define HID 100
#define KPAD 128
#define WSTRIDE 112

// k-major tiled activation layout: element k of row r lives at
//   buf[(r>>6)*(HID*64) + k*64 + (r&63)]
__device__ __forceinline__ size_t buf_base(int row) {
  return (size_t)(row >> 6) * (HID * 64) + (row & 63);
}

// Fast tanh: 1 - 2/(exp2(2*log2e*x)+1). v_exp_f32 (1ulp) + rcp + 1 Newton.
// Error ~2.5e-4 in r-units -> candidate q within +-1 of exact; table snaps it.
__device__ __forceinline__ float fast_tanh(float x) {
  float y = x * 2.885390081777927f;            // 2*log2(e)
  y = fminf(y, 126.0f);                        // avoid inf -> NaN in NR
  const float t = __builtin_amdgcn_exp2f(y);
  const float d = t + 1.0f;
  float r0 = __builtin_amdgcn_rcpf(d);
  r0 = fmaf(fmaf(-d, r0, 1.0f), r0, r0);       // Newton: ~1ulp reciprocal
  return fmaf(-2.0f, r0, 1.0f);
}

// Exact table-snapped quant+materialize: decisions == fl32(tanh64) semantics.
// Bs[j] = minimal fp32 pre with decision >= j-127 (Bs[0]=-inf, Bs[255]=+inf).
__device__ __forceinline__ float qtab(float pre, float sx, float isx,
                                      const float* Bs) {
  float rr = rintf(fast_tanh(pre) * isx);
  rr = fminf(fmaxf(rr, -127.0f), 127.0f);
  const int j = (int)rr + 127;                 // 0..254
  const float bl = Bs[j];
  const float bh = Bs[j + 1];
  if (pre >= bh) rr += 1.0f;                   // -> cndmask chain
  else if (pre < bl) rr -= 1.0f;
  return rr * sx;                              // fp32 materialization, like np
}

#define FOR25(M) M(0) M(1) M(2) M(3) M(4) M(5) M(6) M(7) M(8) M(9) M(10) \
  M(11) M(12) M(13) M(14) M(15) M(16) M(17) M(18) M(19) M(20) M(21) M(22) M(23) M(24)

// ---------------- input max ------------------------------------------------
__global__ __launch_bounds__(256) void inmax_kernel(const float* __restrict__ z,
                                                    const float* __restrict__ t,
                                                    int* __restrict__ inbits) {
  float m = 0.0f;
  const int stride = gridDim.x * blockDim.x;
  for (int i = blockIdx.x * blockDim.x + threadIdx.x; i < N_PTS; i += stride) {
    m = fmaxf(m, fabsf(z[i]));
    m = fmaxf(m, fabsf(t[i]));
  }
  __shared__ float red[256];
  red[threadIdx.x] = m;
  __syncthreads();
  for (int s = 128; s > 0; s >>= 1) {
    if (threadIdx.x < s) red[threadIdx.x] = fmaxf(red[threadIdx.x], red[threadIdx.x + s]);
    __syncthreads();
  }
  if (threadIdx.x == 0) atomicMax(inbits, __float_as_int(red[0]));  // non-neg bits
}

// ---------------- weight prep ----------------------------------------------
__global__ __launch_bounds__(256) void prep_kernel(
    const float* __restrict__ W1, const float* __restrict__ W2, const float* __restrict__ W3,
    const float* __restrict__ W4, const float* __restrict__ W5, const float* __restrict__ W6,
    const float* __restrict__ Wout,
    float* __restrict__ wq32, float* __restrict__ w1c0, float* __restrict__ w1c1,
    float* __restrict__ wo0, float* __restrict__ wo1, float* __restrict__ swv) {
  const int b = blockIdx.x;
  const float* W;
  int n;
  if (b < 5) { W = (b == 0) ? W2 : (b == 1) ? W3 : (b == 2) ? W4 : (b == 3) ? W5 : W6; n = HID * HID; }
  else if (b == 5) { W = W1; n = HID * 2; }
  else { W = Wout; n = 2 * HID; }

  float m = 0.0f;
  for (int i = threadIdx.x; i < n; i += 256) m = fmaxf(m, fabsf(W[i]));
  __shared__ float red[256];
  red[threadIdx.x] = m;
  __syncthreads();
  for (int s = 128; s > 0; s >>= 1) {
    if (threadIdx.x < s) red[threadIdx.x] = fmaxf(red[threadIdx.x], red[threadIdx.x + s]);
    __syncthreads();
  }
  const float sw = fmaxf(red[0] / 127.0f, 1e-12f);
  if (threadIdx.x == 0) {
    const int layer = (b < 5) ? (b + 2) : ((b == 5) ? 1 : 7);
    swv[layer] = sw;
  }
  if (b < 5) {
    float* dst = wq32 + (size_t)b * HID * WSTRIDE;
    for (int i = threadIdx.x; i < HID * WSTRIDE; i += 256) {
      const int r = i / WSTRIDE, k = i - r * WSTRIDE;
      float v = 0.0f;
      if (k < HID) {
        float q = rintf(W[r * HID + k] / sw);
        q = fminf(fmaxf(q, -127.0f), 127.0f);
        v = q * sw;
      }
      dst[i] = v;
    }
  } else if (b == 5) {
    for (int j = threadIdx.x; j < HID; j += 256) {
      float q0 = rintf(W[j * 2 + 0] / sw);
      q0 = fminf(fmaxf(q0, -127.0f), 127.0f);
      w1c0[j] = q0 * sw;
      float q1 = rintf(W[j * 2 + 1] / sw);
      q1 = fminf(fmaxf(q1, -127.0f), 127.0f);
      w1c1[j] = q1 * sw;
    }
  } else {
    for (int k = threadIdx.x; k < HID; k += 256) {
      float q0 = rintf(W[k] / sw);
      q0 = fminf(fmaxf(q0, -127.0f), 127.0f);
      wo0[k] = q0 * sw;
      float q1 = rintf(W[HID + k] / sw);
      q1 = fminf(fmaxf(q1, -127.0f), 127.0f);
      wo1[k] = q1 * sw;
    }
  }
}

// ---------------- scale chain + exact boundary table -----------------------
__global__ void scale_kernel(int stage, const float* __restrict__ bnext, int nbn,
                             const float* __restrict__ swv, float* __restrict__ sxv,
                             float* __restrict__ bq32, float* __restrict__ Bt,
                             const int* __restrict__ maxpre, const int* __restrict__ inbits) {
  __shared__ float s_sb, s_sx;
  if (threadIdx.x == 0) {
    float sx;
    if (stage == 0) {
      sx = __int_as_float(inbits[0]) / 127.0f;
    } else {
      const float mp = __int_as_float(maxpre[stage]);
      sx = (float)tanh((double)mp) / 127.0f;   // fl32(tanh64(maxpre)), fp32 div
    }
    sx = fmaxf(sx, 1e-12f);
    sxv[stage] = sx;
    s_sx = sx;
    s_sb = sx * swv[stage + 1];
  }
  __syncthreads();
  const float sb = s_sb;
  const float sx = s_sx;
  for (int j = threadIdx.x; j < KPAD; j += blockDim.x) {
    float v = 0.0f;
    if (j < nbn) {
      float q = rintf(bnext[j] / sb);
      q = fminf(fmaxf(q, -128.0f), 127.0f);    // Int8Bias clip
      v = q * sb;
    }
    bq32[(stage + 1) * KPAD + j] = v;
  }
  if (stage >= 1) {
    // exact pre-space decision boundaries for decision(pre)=rintf(fl32(tanh64(pre))/sx)
    float* B = Bt + stage * 256;
    for (int j = threadIdx.x; j < 256; j += blockDim.x) {
      float val;
      if (j == 0) {
        val = -INFINITY;
      } else if (j == 255) {
        val = INFINITY;
      } else {
        const int q = j - 127;
        const float qf = (float)q;
        // 1) minimal fp32 h with rintf(h/sx) >= q  (exact predicate walk)
        float h = (float)((double)sx * ((double)q - 0.5));
        if (rintf(h / sx) >= qf) {
          for (int it = 0; it < 4000; ++it) {
            const float dn = nextafterf(h, -INFINITY);
            if (!(rintf(dn / sx) >= qf)) break;
            h = dn;
          }
        } else {
          for (int it = 0; it < 4000; ++it) {
            h = nextafterf(h, INFINITY);
            if (rintf(h / sx) >= qf) break;
          }
        }
        // 2) minimal fp32 pre with fl32(tanh64(pre)) >= h (exact predicate walk;
        //    seed from atanh of the rounding midpoint so the seed is ~1 ulp off)
        const double hmid = 0.5 * ((double)h + (double)nextafterf(h, -INFINITY));
        float pre = (float)atanh(hmid);
        if ((float)tanh((double)pre) >= h) {
          for (int it = 0; it < 4000; ++it) {
            const float dn = nextafterf(pre, -INFINITY);
            if (!((float)tanh((double)dn) >= h)) break;
            pre = dn;
          }
        } else {
          for (int it = 0; it < 4000; ++it) {
            pre = nextafterf(pre, INFINITY);
            if ((float)tanh((double)pre) >= h) break;
          }
        }
        val = pre;
      }
      B[j] = val;
    }
  }
}

// ---------------- layer 1 --------------------------------------------------
__global__ __launch_bounds__(256) void layer1_kernel(
    const float* __restrict__ z, const float* __restrict__ t,
    const float* __restrict__ w1c0, const float* __restrict__ w1c1,
    const float* __restrict__ bq32, const float* __restrict__ sxv,
    float* __restrict__ buf, int* __restrict__ maxpre) {
  const float sx0 = sxv[0];
  const int row = blockIdx.x * 256 + threadIdx.x;
  float qz = rintf(z[row] / sx0);
  qz = fminf(fmaxf(qz, -127.0f), 127.0f);
  const float xz = qz * sx0;
  float qt = rintf(t[row] / sx0);
  qt = fminf(fmaxf(qt, -127.0f), 127.0f);
  const float xt = qt * sx0;

  float m = 0.0f;
  float* out = buf + buf_base(row);
#pragma unroll 4
  for (int j = 0; j < HID; ++j) {
    const float mm = fmaf(xt, w1c1[j], xz * w1c0[j]);
    const float pre = mm + bq32[KPAD + j];
    out[j * 64] = pre;
    m = fmaxf(m, fabsf(pre));
  }
  __shared__ float red[256];
  red[threadIdx.x] = m;
  __syncthreads();
  for (int s = 128; s > 0; s >>= 1) {
    if (threadIdx.x < s) red[threadIdx.x] = fmaxf(red[threadIdx.x], red[threadIdx.x + s]);
    __syncthreads();
  }
  if (threadIdx.x == 0) atomicMax(maxpre, __float_as_int(red[0]));
}

// ---------------- layers 2..6: xq in NAMED registers, table quant ----------
__global__ __launch_bounds__(256, 3) void layer_mid_kernel(
    float* buf, const float* __restrict__ wq, const float* __restrict__ bq,
    const float* __restrict__ sxp, const float* __restrict__ Btab,
    int* __restrict__ maxpre) {
  __shared__ float Bs[256];
  __shared__ float red[256];
  Bs[threadIdx.x] = Btab[threadIdx.x];
  __syncthreads();

  const float sx = sxp[0];
  const float isx = 1.0f / sx;
  const int row = blockIdx.x * 256 + threadIdx.x;
  float* rp = buf + buf_base(row);

#define DECL4(i) float4 x##i;
  FOR25(DECL4)
#undef DECL4
#define LOAD4(i)                 \
  x##i.x = rp[(4 * i + 0) * 64]; \
  x##i.y = rp[(4 * i + 1) * 64]; \
  x##i.z = rp[(4 * i + 2) * 64]; \
  x##i.w = rp[(4 * i + 3) * 64];
  FOR25(LOAD4)
#undef LOAD4

#define Q4(i)                          \
  x##i.x = qtab(x##i.x, sx, isx, Bs);  \
  x##i.y = qtab(x##i.y, sx, isx, Bs);  \
  x##i.z = qtab(x##i.z, sx, isx, Bs);  \
  x##i.w = qtab(x##i.w, sx, isx, Bs);
  FOR25(Q4)
#undef Q4

  float m = 0.0f;
#define FMA4(i)                            \
  a0 = fmaf(x##i.x, wr[4 * i + 0], a0);    \
  a1 = fmaf(x##i.y, wr[4 * i + 1], a1);    \
  a2 = fmaf(x##i.z, wr[4 * i + 2], a2);    \
  a3 = fmaf(x##i.w, wr[4 * i + 3], a3);
#define DOTJ(e, dst) {                                   \
    const float* wr = wq + (j4 * 4 + (e)) * WSTRIDE;     \
    float a0 = 0.0f, a1 = 0.0f, a2 = 0.0f, a3 = 0.0f;    \
    FOR25(FMA4)                                          \
    dst = ((a0 + a1) + (a2 + a3)) + bq[j4 * 4 + (e)]; }
  for (int j4 = 0; j4 < 25; ++j4) {
    float s0, s1, s2, s3;
    DOTJ(0, s0) DOTJ(1, s1) DOTJ(2, s2) DOTJ(3, s3)
    m = fmaxf(m, fabsf(s0)); m = fmaxf(m, fabsf(s1));
    m = fmaxf(m, fabsf(s2)); m = fmaxf(m, fabsf(s3));
    rp[(j4 * 4 + 0) * 64] = s0;
    rp[(j4 * 4 + 1) * 64] = s1;
    rp[(j4 * 4 + 2) * 64] = s2;
    rp[(j4 * 4 + 3) * 64] = s3;
  }
#undef DOTJ
#undef FMA4

  red[threadIdx.x] = m;
  __syncthreads();
  for (int s = 128; s > 0; s >>= 1) {
    if (threadIdx.x < s) red[threadIdx.x] = fmaxf(red[threadIdx.x], red[threadIdx.x + s]);
    __syncthreads();
  }
  if (threadIdx.x == 0) atomicMax(maxpre, __float_as_int(red[0]));
}

// ---------------- output layer ---------------------------------------------
__global__ __launch_bounds__(256) void layer_out_kernel(
    const float* __restrict__ buf, const float* __restrict__ wo0, const float* __restrict__ wo1,
    const float* __restrict__ bq32, const float* __restrict__ sxp,
    const float* __restrict__ Btab, float* __restrict__ out) {
  __shared__ float Bs[256];
  Bs[threadIdx.x] = Btab[threadIdx.x];
  __syncthreads();
  const float sx = sxp[0];
  const float isx = 1.0f / sx;
  const int row = blockIdx.x * blockDim.x + threadIdx.x;
  const float* rp = buf + buf_base(row);
  float a00 = 0.0f, a01 = 0.0f, a02 = 0.0f, a03 = 0.0f;
  float a10 = 0.0f, a11 = 0.0f, a12 = 0.0f, a13 = 0.0f;
  for (int k4 = 0; k4 < 25; ++k4) {
    const int k = k4 * 4;
    const float x0 = qtab(rp[(k + 0) * 64], sx, isx, Bs);
    const float x1 = qtab(rp[(k + 1) * 64], sx, isx, Bs);
    const float x2 = qtab(rp[(k + 2) * 64], sx, isx, Bs);
    const float x3 = qtab(rp[(k + 3) * 64], sx, isx, Bs);
    a00 = fmaf(x0, wo0[k + 0], a00); a10 = fmaf(x0, wo1[k + 0], a10);
    a01 = fmaf(x1, wo0[k + 1], a01); a11 = fmaf(x1, wo1[k + 1], a11);
    a02 = fmaf(x2, wo0[k + 2], a02); a12 = fmaf(x2, wo1[k + 2], a12);
    a03 = fmaf(x3, wo0[k + 3], a03); a13 = fmaf(x3, wo1[k + 3], a13);
  }
  float2 o;
  o.x = ((a00 + a01) + (a02 + a03)) + bq32[7 * KPAD + 0];
  o.y = ((a10 + a11) + (a12 + a13)) + bq32[7 * KPAD + 1];
  *(float2*)(out + (size_t)row * 2) = o;
}

extern "C" void kernel_launch(void* const* d_in, const int* in_sizes, int n_in,
                              void* d_out, int out_size, void* d_ws, size_t ws_size,
                              hipStream_t stream) {
  const float* z = (const float*)d_in[0];
  const float* t = (const float*)d_in[1];
  const float* Wp[8];
  const float* Bp[8];
  for (int l = 1; l <= 7; ++l) {
    Wp[l] = (const float*)d_in[2 * l];
    Bp[l] = (const float*)d_in[2 * l + 1];
  }

  char* ws = (char*)d_ws;
  size_t off = 0;
  float* buf = (float*)(ws + off);    off += (size_t)N_PTS * HID * sizeof(float);       // 105 MB
  float* wq32 = (float*)(ws + off);   off += (size_t)5 * HID * WSTRIDE * sizeof(float);  // 224 KB
  float* w1c0 = (float*)(ws + off);   off += 128 * sizeof(float);
  float* w1c1 = (float*)(ws + off);   off += 128 * sizeof(float);
  float* wo0 = (float*)(ws + off);    off += 128 * sizeof(float);
  float* wo1 = (float*)(ws + off);    off += 128 * sizeof(float);
  float* bq32 = (float*)(ws + off);   off += 8 * KPAD * sizeof(float);
  float* Bt = (float*)(ws + off);     off += 8 * 256 * sizeof(float);
  float* swv = (float*)(ws + off);    off += 16 * sizeof(float);
  float* sxv = (float*)(ws + off);    off += 16 * sizeof(float);
  int* maxpre = (int*)(ws + off);     off += 16 * sizeof(int);  // 0xAA poison negative: atomicMax-safe
  int* inbits = (int*)(ws + off);     off += 16 * sizeof(int);
  (void)ws_size; (void)in_sizes; (void)n_in; (void)out_size;

  inmax_kernel<<<512, 256, 0, stream>>>(z, t, inbits);
  prep_kernel<<<7, 256, 0, stream>>>(Wp[1], Wp[2], Wp[3], Wp[4], Wp[5], Wp[6], Wp[7],
                                     wq32, w1c0, w1c1, wo0, wo1, swv);
  scale_kernel<<<1, 256, 0, stream>>>(0, Bp[1], HID, swv, sxv, bq32, Bt, maxpre, inbits);
  layer1_kernel<<<N_PTS / 256, 256, 0, stream>>>(z, t, w1c0, w1c1, bq32, sxv, buf, maxpre + 1);
  for (int l = 2; l <= 6; ++l) {
    scale_kernel<<<1, 256, 0, stream>>>(l - 1, Bp[l], HID, swv, sxv, bq32, Bt, maxpre, inbits);
    layer_mid_kernel<<<N_PTS / 256, 256, 0, stream>>>(buf, wq32 + (size_t)(l - 2) * HID * WSTRIDE,
                                                      bq32 + l * KPAD, sxv + (l - 1),
                                                      Bt + (l - 1) * 256, maxpre + l);
  }
  scale_kernel<<<1, 256, 0, stream>>>(6, Bp[7], 2, swv, sxv, bq32, Bt, maxpre, inbits);
  layer_out_kernel<<<N_PTS / 256, 256, 0, stream>>>(buf, wo0, wo1, bq32, sxv + 6,
                                                    Bt + 6 * 256, (float*)d_out);
}

// Round 8
// 1376.527 us; speedup vs baseline: 1.1489x; 1.1489x over previous
//
#include <hip/hip_runtime.h>
#include <stdint.h>

#define N_PTS 262144
#define HID 100
#define KPAD 128
#define WSTRIDE 112

// k-major tiled activation layout: element k of row r lives at
//   buf[(r>>6)*(HID*64) + k*64 + (r&63)]
__device__ __forceinline__ size_t buf_base(int row) {
  return (size_t)(row >> 6) * (HID * 64) + (row & 63);
}

// Fast tanh: 1 - 2/(exp2(2*log2e*x)+1). v_exp_f32 (1ulp) + rcp + 1 Newton.
// Error ~2.5e-4 in r-units -> candidate q within +-1 of exact; table snaps it.
__device__ __forceinline__ float fast_tanh(float x) {
  float y = x * 2.885390081777927f;            // 2*log2(e)
  y = fminf(y, 126.0f);                        // avoid inf -> NaN in NR
  const float t = __builtin_amdgcn_exp2f(y);
  const float d = t + 1.0f;
  float r0 = __builtin_amdgcn_rcpf(d);
  r0 = fmaf(fmaf(-d, r0, 1.0f), r0, r0);       // Newton: ~1ulp reciprocal
  return fmaf(-2.0f, r0, 1.0f);
}

// Exact table-snapped quant+materialize: decisions == fl32(tanh64) semantics.
// Bs[j] = minimal fp32 pre with decision >= j-127 (Bs[0]=-inf, Bs[255]=+inf).
__device__ __forceinline__ float qtab(float pre, float sx, float isx,
                                      const float* Bs) {
  float rr = rintf(fast_tanh(pre) * isx);
  rr = fminf(fmaxf(rr, -127.0f), 127.0f);
  const int j = (int)rr + 127;                 // 0..254
  const float bl = Bs[j];
  const float bh = Bs[j + 1];
  if (pre >= bh) rr += 1.0f;                   // -> cndmask chain
  else if (pre < bl) rr -= 1.0f;
  return rr * sx;                              // fp32 materialization, like np
}

#define FOR25(M) M(0) M(1) M(2) M(3) M(4) M(5) M(6) M(7) M(8) M(9) M(10) \
  M(11) M(12) M(13) M(14) M(15) M(16) M(17) M(18) M(19) M(20) M(21) M(22) M(23) M(24)

// ---------------- input max ------------------------------------------------
__global__ __launch_bounds__(256) void inmax_kernel(const float* __restrict__ z,
                                                    const float* __restrict__ t,
                                                    int* __restrict__ inbits) {
  float m = 0.0f;
  const int stride = gridDim.x * blockDim.x;
  for (int i = blockIdx.x * blockDim.x + threadIdx.x; i < N_PTS; i += stride) {
    m = fmaxf(m, fabsf(z[i]));
    m = fmaxf(m, fabsf(t[i]));
  }
  __shared__ float red[256];
  red[threadIdx.x] = m;
  __syncthreads();
  for (int s = 128; s > 0; s >>= 1) {
    if (threadIdx.x < s) red[threadIdx.x] = fmaxf(red[threadIdx.x], red[threadIdx.x + s]);
    __syncthreads();
  }
  if (threadIdx.x == 0) atomicMax(inbits, __float_as_int(red[0]));  // non-neg bits
}

// ---------------- weight prep ----------------------------------------------
__global__ __launch_bounds__(256) void prep_kernel(
    const float* __restrict__ W1, const float* __restrict__ W2, const float* __restrict__ W3,
    const float* __restrict__ W4, const float* __restrict__ W5, const float* __restrict__ W6,
    const float* __restrict__ Wout,
    float* __restrict__ wq32, float* __restrict__ w1c0, float* __restrict__ w1c1,
    float* __restrict__ wo0, float* __restrict__ wo1, float* __restrict__ swv) {
  const int b = blockIdx.x;
  const float* W;
  int n;
  if (b < 5) { W = (b == 0) ? W2 : (b == 1) ? W3 : (b == 2) ? W4 : (b == 3) ? W5 : W6; n = HID * HID; }
  else if (b == 5) { W = W1; n = HID * 2; }
  else { W = Wout; n = 2 * HID; }

  float m = 0.0f;
  for (int i = threadIdx.x; i < n; i += 256) m = fmaxf(m, fabsf(W[i]));
  __shared__ float red[256];
  red[threadIdx.x] = m;
  __syncthreads();
  for (int s = 128; s > 0; s >>= 1) {
    if (threadIdx.x < s) red[threadIdx.x] = fmaxf(red[threadIdx.x], red[threadIdx.x + s]);
    __syncthreads();
  }
  const float sw = fmaxf(red[0] / 127.0f, 1e-12f);
  if (threadIdx.x == 0) {
    const int layer = (b < 5) ? (b + 2) : ((b == 5) ? 1 : 7);
    swv[layer] = sw;
  }
  if (b < 5) {
    float* dst = wq32 + (size_t)b * HID * WSTRIDE;
    for (int i = threadIdx.x; i < HID * WSTRIDE; i += 256) {
      const int r = i / WSTRIDE, k = i - r * WSTRIDE;
      float v = 0.0f;
      if (k < HID) {
        float q = rintf(W[r * HID + k] / sw);
        q = fminf(fmaxf(q, -127.0f), 127.0f);
        v = q * sw;
      }
      dst[i] = v;
    }
  } else if (b == 5) {
    for (int j = threadIdx.x; j < HID; j += 256) {
      float q0 = rintf(W[j * 2 + 0] / sw);
      q0 = fminf(fmaxf(q0, -127.0f), 127.0f);
      w1c0[j] = q0 * sw;
      float q1 = rintf(W[j * 2 + 1] / sw);
      q1 = fminf(fmaxf(q1, -127.0f), 127.0f);
      w1c1[j] = q1 * sw;
    }
  } else {
    for (int k = threadIdx.x; k < HID; k += 256) {
      float q0 = rintf(W[k] / sw);
      q0 = fminf(fmaxf(q0, -127.0f), 127.0f);
      wo0[k] = q0 * sw;
      float q1 = rintf(W[HID + k] / sw);
      q1 = fminf(fmaxf(q1, -127.0f), 127.0f);
      wo1[k] = q1 * sw;
    }
  }
}

// ---------------- scale chain + exact boundary table -----------------------
__global__ void scale_kernel(int stage, const float* __restrict__ bnext, int nbn,
                             const float* __restrict__ swv, float* __restrict__ sxv,
                             float* __restrict__ bq32, float* __restrict__ Bt,
                             const int* __restrict__ maxpre, const int* __restrict__ inbits) {
  __shared__ float s_sb, s_sx;
  if (threadIdx.x == 0) {
    float sx;
    if (stage == 0) {
      sx = __int_as_float(inbits[0]) / 127.0f;
    } else {
      const float mp = __int_as_float(maxpre[stage]);
      sx = (float)tanh((double)mp) / 127.0f;   // fl32(tanh64(maxpre)), fp32 div
    }
    sx = fmaxf(sx, 1e-12f);
    sxv[stage] = sx;
    s_sx = sx;
    s_sb = sx * swv[stage + 1];
  }
  __syncthreads();
  const float sb = s_sb;
  const float sx = s_sx;
  for (int j = threadIdx.x; j < KPAD; j += blockDim.x) {
    float v = 0.0f;
    if (j < nbn) {
      float q = rintf(bnext[j] / sb);
      q = fminf(fmaxf(q, -128.0f), 127.0f);    // Int8Bias clip
      v = q * sb;
    }
    bq32[(stage + 1) * KPAD + j] = v;
  }
  if (stage >= 1) {
    // exact pre-space decision boundaries for decision(pre)=rintf(fl32(tanh64(pre))/sx)
    float* B = Bt + stage * 256;
    for (int j = threadIdx.x; j < 256; j += blockDim.x) {
      float val;
      if (j == 0) {
        val = -INFINITY;
      } else if (j == 255) {
        val = INFINITY;
      } else {
        const int q = j - 127;
        const float qf = (float)q;
        // 1) minimal fp32 h with rintf(h/sx) >= q  (exact predicate walk)
        float h = (float)((double)sx * ((double)q - 0.5));
        if (rintf(h / sx) >= qf) {
          for (int it = 0; it < 4000; ++it) {
            const float dn = nextafterf(h, -INFINITY);
            if (!(rintf(dn / sx) >= qf)) break;
            h = dn;
          }
        } else {
          for (int it = 0; it < 4000; ++it) {
            h = nextafterf(h, INFINITY);
            if (rintf(h / sx) >= qf) break;
          }
        }
        // 2) minimal fp32 pre with fl32(tanh64(pre)) >= h (exact predicate walk;
        //    seed from atanh of the rounding midpoint so the seed is ~1 ulp off)
        const double hmid = 0.5 * ((double)h + (double)nextafterf(h, -INFINITY));
        float pre = (float)atanh(hmid);
        if ((float)tanh((double)pre) >= h) {
          for (int it = 0; it < 4000; ++it) {
            const float dn = nextafterf(pre, -INFINITY);
            if (!((float)tanh((double)dn) >= h)) break;
            pre = dn;
          }
        } else {
          for (int it = 0; it < 4000; ++it) {
            pre = nextafterf(pre, INFINITY);
            if ((float)tanh((double)pre) >= h) break;
          }
        }
        val = pre;
      }
      B[j] = val;
    }
  }
}

// ---------------- layer 1 --------------------------------------------------
__global__ __launch_bounds__(256) void layer1_kernel(
    const float* __restrict__ z, const float* __restrict__ t,
    const float* __restrict__ w1c0, const float* __restrict__ w1c1,
    const float* __restrict__ bq32, const float* __restrict__ sxv,
    float* __restrict__ buf, int* __restrict__ maxpre) {
  const float sx0 = sxv[0];
  const int row = blockIdx.x * 256 + threadIdx.x;
  float qz = rintf(z[row] / sx0);
  qz = fminf(fmaxf(qz, -127.0f), 127.0f);
  const float xz = qz * sx0;
  float qt = rintf(t[row] / sx0);
  qt = fminf(fmaxf(qt, -127.0f), 127.0f);
  const float xt = qt * sx0;

  float m = 0.0f;
  float* out = buf + buf_base(row);
#pragma unroll 4
  for (int j = 0; j < HID; ++j) {
    const float mm = fmaf(xt, w1c1[j], xz * w1c0[j]);
    const float pre = mm + bq32[KPAD + j];
    out[j * 64] = pre;
    m = fmaxf(m, fabsf(pre));
  }
  __shared__ float red[256];
  red[threadIdx.x] = m;
  __syncthreads();
  for (int s = 128; s > 0; s >>= 1) {
    if (threadIdx.x < s) red[threadIdx.x] = fmaxf(red[threadIdx.x], red[threadIdx.x + s]);
    __syncthreads();
  }
  if (threadIdx.x == 0) atomicMax(maxpre, __float_as_int(red[0]));
}

// ---------------- layers 2..6: xq in NAMED registers, table quant ----------
// amdgpu_waves_per_eu(3,3): pin the allocator's occupancy TARGET (not just the
// launch_bounds minimum) so the VGPR budget is 512/3~=168 and the 100-float xq
// working set stays in registers instead of being spilled to scratch
// (rounds 6/7: VGPR 96/68 < 100 => xq in scratch, VALUBusy 21%).
__global__ __launch_bounds__(256)
__attribute__((amdgpu_waves_per_eu(3, 3)))
void layer_mid_kernel(
    float* buf, const float* __restrict__ wq, const float* __restrict__ bq,
    const float* __restrict__ sxp, const float* __restrict__ Btab,
    int* __restrict__ maxpre) {
  __shared__ float Bs[256];
  __shared__ float red[256];
  Bs[threadIdx.x] = Btab[threadIdx.x];
  __syncthreads();

  const float sx = sxp[0];
  const float isx = 1.0f / sx;
  const int row = blockIdx.x * 256 + threadIdx.x;
  float* rp = buf + buf_base(row);

#define DECL4(i) float4 x##i;
  FOR25(DECL4)
#undef DECL4
#define LOAD4(i)                 \
  x##i.x = rp[(4 * i + 0) * 64]; \
  x##i.y = rp[(4 * i + 1) * 64]; \
  x##i.z = rp[(4 * i + 2) * 64]; \
  x##i.w = rp[(4 * i + 3) * 64];
  FOR25(LOAD4)
#undef LOAD4

#define Q4(i)                          \
  x##i.x = qtab(x##i.x, sx, isx, Bs);  \
  x##i.y = qtab(x##i.y, sx, isx, Bs);  \
  x##i.z = qtab(x##i.z, sx, isx, Bs);  \
  x##i.w = qtab(x##i.w, sx, isx, Bs);
  FOR25(Q4)
#undef Q4

  float m = 0.0f;
#define FMA4(i)                            \
  a0 = fmaf(x##i.x, wr[4 * i + 0], a0);    \
  a1 = fmaf(x##i.y, wr[4 * i + 1], a1);    \
  a2 = fmaf(x##i.z, wr[4 * i + 2], a2);    \
  a3 = fmaf(x##i.w, wr[4 * i + 3], a3);
#define DOTJ(e, dst) {                                   \
    const float* wr = wq + (j4 * 4 + (e)) * WSTRIDE;     \
    float a0 = 0.0f, a1 = 0.0f, a2 = 0.0f, a3 = 0.0f;    \
    FOR25(FMA4)                                          \
    dst = ((a0 + a1) + (a2 + a3)) + bq[j4 * 4 + (e)]; }
  for (int j4 = 0; j4 < 25; ++j4) {
    float s0, s1, s2, s3;
    DOTJ(0, s0) DOTJ(1, s1) DOTJ(2, s2) DOTJ(3, s3)
    m = fmaxf(m, fabsf(s0)); m = fmaxf(m, fabsf(s1));
    m = fmaxf(m, fabsf(s2)); m = fmaxf(m, fabsf(s3));
    rp[(j4 * 4 + 0) * 64] = s0;
    rp[(j4 * 4 + 1) * 64] = s1;
    rp[(j4 * 4 + 2) * 64] = s2;
    rp[(j4 * 4 + 3) * 64] = s3;
  }
#undef DOTJ
#undef FMA4

  red[threadIdx.x] = m;
  __syncthreads();
  for (int s = 128; s > 0; s >>= 1) {
    if (threadIdx.x < s) red[threadIdx.x] = fmaxf(red[threadIdx.x], red[threadIdx.x + s]);
    __syncthreads();
  }
  if (threadIdx.x == 0) atomicMax(maxpre, __float_as_int(red[0]));
}

// ---------------- output layer ---------------------------------------------
__global__ __launch_bounds__(256) void layer_out_kernel(
    const float* __restrict__ buf, const float* __restrict__ wo0, const float* __restrict__ wo1,
    const float* __restrict__ bq32, const float* __restrict__ sxp,
    const float* __restrict__ Btab, float* __restrict__ out) {
  __shared__ float Bs[256];
  Bs[threadIdx.x] = Btab[threadIdx.x];
  __syncthreads();
  const float sx = sxp[0];
  const float isx = 1.0f / sx;
  const int row = blockIdx.x * blockDim.x + threadIdx.x;
  const float* rp = buf + buf_base(row);
  float a00 = 0.0f, a01 = 0.0f, a02 = 0.0f, a03 = 0.0f;
  float a10 = 0.0f, a11 = 0.0f, a12 = 0.0f, a13 = 0.0f;
  for (int k4 = 0; k4 < 25; ++k4) {
    const int k = k4 * 4;
    const float x0 = qtab(rp[(k + 0) * 64], sx, isx, Bs);
    const float x1 = qtab(rp[(k + 1) * 64], sx, isx, Bs);
    const float x2 = qtab(rp[(k + 2) * 64], sx, isx, Bs);
    const float x3 = qtab(rp[(k + 3) * 64], sx, isx, Bs);
    a00 = fmaf(x0, wo0[k + 0], a00); a10 = fmaf(x0, wo1[k + 0], a10);
    a01 = fmaf(x1, wo0[k + 1], a01); a11 = fmaf(x1, wo1[k + 1], a11);
    a02 = fmaf(x2, wo0[k + 2], a02); a12 = fmaf(x2, wo1[k + 2], a12);
    a03 = fmaf(x3, wo0[k + 3], a03); a13 = fmaf(x3, wo1[k + 3], a13);
  }
  float2 o;
  o.x = ((a00 + a01) + (a02 + a03)) + bq32[7 * KPAD + 0];
  o.y = ((a10 + a11) + (a12 + a13)) + bq32[7 * KPAD + 1];
  *(float2*)(out + (size_t)row * 2) = o;
}

extern "C" void kernel_launch(void* const* d_in, const int* in_sizes, int n_in,
                              void* d_out, int out_size, void* d_ws, size_t ws_size,
                              hipStream_t stream) {
  const float* z = (const float*)d_in[0];
  const float* t = (const float*)d_in[1];
  const float* Wp[8];
  const float* Bp[8];
  for (int l = 1; l <= 7; ++l) {
    Wp[l] = (const float*)d_in[2 * l];
    Bp[l] = (const float*)d_in[2 * l + 1];
  }

  char* ws = (char*)d_ws;
  size_t off = 0;
  float* buf = (float*)(ws + off);    off += (size_t)N_PTS * HID * sizeof(float);       // 105 MB
  float* wq32 = (float*)(ws + off);   off += (size_t)5 * HID * WSTRIDE * sizeof(float);  // 224 KB
  float* w1c0 = (float*)(ws + off);   off += 128 * sizeof(float);
  float* w1c1 = (float*)(ws + off);   off += 128 * sizeof(float);
  float* wo0 = (float*)(ws + off);    off += 128 * sizeof(float);
  float* wo1 = (float*)(ws + off);    off += 128 * sizeof(float);
  float* bq32 = (float*)(ws + off);   off += 8 * KPAD * sizeof(float);
  float* Bt = (float*)(ws + off);     off += 8 * 256 * sizeof(float);
  float* swv = (float*)(ws + off);    off += 16 * sizeof(float);
  float* sxv = (float*)(ws + off);    off += 16 * sizeof(float);
  int* maxpre = (int*)(ws + off);     off += 16 * sizeof(int);  // 0xAA poison negative: atomicMax-safe
  int* inbits = (int*)(ws + off);     off += 16 * sizeof(int);
  (void)ws_size; (void)in_sizes; (void)n_in; (void)out_size;

  inmax_kernel<<<512, 256, 0, stream>>>(z, t, inbits);
  prep_kernel<<<7, 256, 0, stream>>>(Wp[1], Wp[2], Wp[3], Wp[4], Wp[5], Wp[6], Wp[7],
                                     wq32, w1c0, w1c1, wo0, wo1, swv);
  scale_kernel<<<1, 256, 0, stream>>>(0, Bp[1], HID, swv, sxv, bq32, Bt, maxpre, inbits);
  layer1_kernel<<<N_PTS / 256, 256, 0, stream>>>(z, t, w1c0, w1c1, bq32, sxv, buf, maxpre + 1);
  for (int l = 2; l <= 6; ++l) {
    scale_kernel<<<1, 256, 0, stream>>>(l - 1, Bp[l], HID, swv, sxv, bq32, Bt, maxpre, inbits);
    layer_mid_kernel<<<N_PTS / 256, 256, 0, stream>>>(buf, wq32 + (size_t)(l - 2) * HID * WSTRIDE,
                                                      bq32 + l * KPAD, sxv + (l - 1),
                                                      Bt + (l - 1) * 256, maxpre + l);
  }
  scale_kernel<<<1, 256, 0, stream>>>(6, Bp[7], 2, swv, sxv, bq32, Bt, maxpre, inbits);
  layer_out_kernel<<<N_PTS / 256, 256, 0, stream>>>(buf, wo0, wo1, bq32, sxv + 6,
                                                    Bt + 6 * 256, (float*)d_out);
}

// Round 9
// 848.314 us; speedup vs baseline: 1.8643x; 1.6227x over previous
//
#include <hip/hip_runtime.h>
#include <stdint.h>

#define N_PTS 262144
#define HID 100
#define KPAD 128
#define WSTRIDE 112

// k-major tiled activation layout: element k of row r lives at
//   buf[(r>>6)*(HID*64) + k*64 + (r&63)]
__device__ __forceinline__ size_t buf_base(int row) {
  return (size_t)(row >> 6) * (HID * 64) + (row & 63);
}

// Fast tanh: 1 - 2/(exp2(2*log2e*x)+1). v_exp_f32 (1ulp) + rcp + 1 Newton.
// Error ~2.5e-4 in r-units -> candidate q within +-1 of exact; table snaps it.
__device__ __forceinline__ float fast_tanh(float x) {
  float y = x * 2.885390081777927f;            // 2*log2(e)
  y = fminf(y, 126.0f);                        // avoid inf -> NaN in NR
  const float t = __builtin_amdgcn_exp2f(y);
  const float d = t + 1.0f;
  float r0 = __builtin_amdgcn_rcpf(d);
  r0 = fmaf(fmaf(-d, r0, 1.0f), r0, r0);       // Newton: ~1ulp reciprocal
  return fmaf(-2.0f, r0, 1.0f);
}

// Exact table-snapped quantization DECISION (int in [-127,127]):
// decisions == rintf(fl32(tanh64(pre))/sx) semantics, via boundary table.
__device__ __forceinline__ int qtabi(float pre, float isx, const float* Bs) {
  float rr = rintf(fast_tanh(pre) * isx);
  rr = fminf(fmaxf(rr, -127.0f), 127.0f);
  const int j = (int)rr + 127;                 // 0..254
  int q = (int)rr;
  if (pre >= Bs[j + 1]) q += 1;                // Bs[255]=+inf guards top
  else if (pre < Bs[j]) q -= 1;                // Bs[0]=-inf guards bottom
  return q;
}

// Float-returning variant (for layer_out), materialized q*sx like np.
__device__ __forceinline__ float qtab(float pre, float sx, float isx,
                                      const float* Bs) {
  return (float)qtabi(pre, isx, Bs) * sx;
}

#define FOR10(M) M(0) M(1) M(2) M(3) M(4) M(5) M(6) M(7) M(8) M(9)

// ---------------- input max ------------------------------------------------
__global__ __launch_bounds__(256) void inmax_kernel(const float* __restrict__ z,
                                                    const float* __restrict__ t,
                                                    int* __restrict__ inbits) {
  float m = 0.0f;
  const int stride = gridDim.x * blockDim.x;
  for (int i = blockIdx.x * blockDim.x + threadIdx.x; i < N_PTS; i += stride) {
    m = fmaxf(m, fabsf(z[i]));
    m = fmaxf(m, fabsf(t[i]));
  }
  __shared__ float red[256];
  red[threadIdx.x] = m;
  __syncthreads();
  for (int s = 128; s > 0; s >>= 1) {
    if (threadIdx.x < s) red[threadIdx.x] = fmaxf(red[threadIdx.x], red[threadIdx.x + s]);
    __syncthreads();
  }
  if (threadIdx.x == 0) atomicMax(inbits, __float_as_int(red[0]));  // non-neg bits
}

// ---------------- weight prep ----------------------------------------------
__global__ __launch_bounds__(256) void prep_kernel(
    const float* __restrict__ W1, const float* __restrict__ W2, const float* __restrict__ W3,
    const float* __restrict__ W4, const float* __restrict__ W5, const float* __restrict__ W6,
    const float* __restrict__ Wout,
    float* __restrict__ wq32, float* __restrict__ w1c0, float* __restrict__ w1c1,
    float* __restrict__ wo0, float* __restrict__ wo1, float* __restrict__ swv) {
  const int b = blockIdx.x;
  const float* W;
  int n;
  if (b < 5) { W = (b == 0) ? W2 : (b == 1) ? W3 : (b == 2) ? W4 : (b == 3) ? W5 : W6; n = HID * HID; }
  else if (b == 5) { W = W1; n = HID * 2; }
  else { W = Wout; n = 2 * HID; }

  float m = 0.0f;
  for (int i = threadIdx.x; i < n; i += 256) m = fmaxf(m, fabsf(W[i]));
  __shared__ float red[256];
  red[threadIdx.x] = m;
  __syncthreads();
  for (int s = 128; s > 0; s >>= 1) {
    if (threadIdx.x < s) red[threadIdx.x] = fmaxf(red[threadIdx.x], red[threadIdx.x + s]);
    __syncthreads();
  }
  const float sw = fmaxf(red[0] / 127.0f, 1e-12f);
  if (threadIdx.x == 0) {
    const int layer = (b < 5) ? (b + 2) : ((b == 5) ? 1 : 7);
    swv[layer] = sw;
  }
  if (b < 5) {
    float* dst = wq32 + (size_t)b * HID * WSTRIDE;
    for (int i = threadIdx.x; i < HID * WSTRIDE; i += 256) {
      const int r = i / WSTRIDE, k = i - r * WSTRIDE;
      float v = 0.0f;
      if (k < HID) {
        float q = rintf(W[r * HID + k] / sw);
        q = fminf(fmaxf(q, -127.0f), 127.0f);
        v = q * sw;
      }
      dst[i] = v;
    }
  } else if (b == 5) {
    for (int j = threadIdx.x; j < HID; j += 256) {
      float q0 = rintf(W[j * 2 + 0] / sw);
      q0 = fminf(fmaxf(q0, -127.0f), 127.0f);
      w1c0[j] = q0 * sw;
      float q1 = rintf(W[j * 2 + 1] / sw);
      q1 = fminf(fmaxf(q1, -127.0f), 127.0f);
      w1c1[j] = q1 * sw;
    }
  } else {
    for (int k = threadIdx.x; k < HID; k += 256) {
      float q0 = rintf(W[k] / sw);
      q0 = fminf(fmaxf(q0, -127.0f), 127.0f);
      wo0[k] = q0 * sw;
      float q1 = rintf(W[HID + k] / sw);
      q1 = fminf(fmaxf(q1, -127.0f), 127.0f);
      wo1[k] = q1 * sw;
    }
  }
}

// ---------------- scale chain + exact boundary table -----------------------
__global__ void scale_kernel(int stage, const float* __restrict__ bnext, int nbn,
                             const float* __restrict__ swv, float* __restrict__ sxv,
                             float* __restrict__ bq32, float* __restrict__ Bt,
                             const int* __restrict__ maxpre, const int* __restrict__ inbits) {
  __shared__ float s_sb, s_sx;
  if (threadIdx.x == 0) {
    float sx;
    if (stage == 0) {
      sx = __int_as_float(inbits[0]) / 127.0f;
    } else {
      const float mp = __int_as_float(maxpre[stage]);
      sx = (float)tanh((double)mp) / 127.0f;   // fl32(tanh64(maxpre)), fp32 div
    }
    sx = fmaxf(sx, 1e-12f);
    sxv[stage] = sx;
    s_sx = sx;
    s_sb = sx * swv[stage + 1];
  }
  __syncthreads();
  const float sb = s_sb;
  const float sx = s_sx;
  for (int j = threadIdx.x; j < KPAD; j += blockDim.x) {
    float v = 0.0f;
    if (j < nbn) {
      float q = rintf(bnext[j] / sb);
      q = fminf(fmaxf(q, -128.0f), 127.0f);    // Int8Bias clip
      v = q * sb;
    }
    bq32[(stage + 1) * KPAD + j] = v;
  }
  if (stage >= 1) {
    // exact pre-space decision boundaries for decision(pre)=rintf(fl32(tanh64(pre))/sx)
    float* B = Bt + stage * 256;
    for (int j = threadIdx.x; j < 256; j += blockDim.x) {
      float val;
      if (j == 0) {
        val = -INFINITY;
      } else if (j == 255) {
        val = INFINITY;
      } else {
        const int q = j - 127;
        const float qf = (float)q;
        // 1) minimal fp32 h with rintf(h/sx) >= q  (exact predicate walk)
        float h = (float)((double)sx * ((double)q - 0.5));
        if (rintf(h / sx) >= qf) {
          for (int it = 0; it < 4000; ++it) {
            const float dn = nextafterf(h, -INFINITY);
            if (!(rintf(dn / sx) >= qf)) break;
            h = dn;
          }
        } else {
          for (int it = 0; it < 4000; ++it) {
            h = nextafterf(h, INFINITY);
            if (rintf(h / sx) >= qf) break;
          }
        }
        // 2) minimal fp32 pre with fl32(tanh64(pre)) >= h
        const double hmid = 0.5 * ((double)h + (double)nextafterf(h, -INFINITY));
        float pre = (float)atanh(hmid);
        if ((float)tanh((double)pre) >= h) {
          for (int it = 0; it < 4000; ++it) {
            const float dn = nextafterf(pre, -INFINITY);
            if (!((float)tanh((double)dn) >= h)) break;
            pre = dn;
          }
        } else {
          for (int it = 0; it < 4000; ++it) {
            pre = nextafterf(pre, INFINITY);
            if ((float)tanh((double)pre) >= h) break;
          }
        }
        val = pre;
      }
      B[j] = val;
    }
  }
}

// ---------------- layer 1 --------------------------------------------------
__global__ __launch_bounds__(256) void layer1_kernel(
    const float* __restrict__ z, const float* __restrict__ t,
    const float* __restrict__ w1c0, const float* __restrict__ w1c1,
    const float* __restrict__ bq32, const float* __restrict__ sxv,
    float* __restrict__ buf, int* __restrict__ maxpre) {
  const float sx0 = sxv[0];
  const int row = blockIdx.x * 256 + threadIdx.x;
  float qz = rintf(z[row] / sx0);
  qz = fminf(fmaxf(qz, -127.0f), 127.0f);
  const float xz = qz * sx0;
  float qt = rintf(t[row] / sx0);
  qt = fminf(fmaxf(qt, -127.0f), 127.0f);
  const float xt = qt * sx0;

  float m = 0.0f;
  float* out = buf + buf_base(row);
#pragma unroll 4
  for (int j = 0; j < HID; ++j) {
    const float mm = fmaf(xt, w1c1[j], xz * w1c0[j]);
    const float pre = mm + bq32[KPAD + j];
    out[j * 64] = pre;
    m = fmaxf(m, fabsf(pre));
  }
  __shared__ float red[256];
  red[threadIdx.x] = m;
  __syncthreads();
  for (int s = 128; s > 0; s >>= 1) {
    if (threadIdx.x < s) red[threadIdx.x] = fmaxf(red[threadIdx.x], red[threadIdx.x + s]);
    __syncthreads();
  }
  if (threadIdx.x == 0) atomicMax(maxpre, __float_as_int(red[0]));
}

// ---------------- layers 2..6: 2-phase, low register pressure --------------
// Phase 0: quantize row -> int8 codes packed 4/u32 (exact qtab decisions).
// Phase 1: j-tiled GEMM, 10 outputs/tile = 40 named accumulators; per k4-step
// reload 1 packed u32 (L2-hot, 25.6KB/block), unpack (float)q*sx (== rr*sx
// materialization), split-4 FMA order IDENTICAL to rounds 4-8 -> bitwise-same.
__global__ __launch_bounds__(256) void layer_mid_kernel(
    float* buf, unsigned int* xpq, const float* __restrict__ wq,
    const float* __restrict__ bq, const float* __restrict__ sxp,
    const float* __restrict__ Btab, int* __restrict__ maxpre) {
  __shared__ float Bs[256];
  __shared__ float red[256];
  Bs[threadIdx.x] = Btab[threadIdx.x];
  __syncthreads();

  const float sx = sxp[0];
  const float isx = 1.0f / sx;
  const int row = blockIdx.x * 256 + threadIdx.x;
  float* rp = buf + buf_base(row);
  unsigned int* xp = xpq + (size_t)(row >> 6) * (25 * 64) + (row & 63);

  // ---- phase 0: quantize + pack (coalesced; ~12 live regs) ----
  for (int k4 = 0; k4 < 25; ++k4) {
    const float f0 = rp[(4 * k4 + 0) * 64];
    const float f1 = rp[(4 * k4 + 1) * 64];
    const float f2 = rp[(4 * k4 + 2) * 64];
    const float f3 = rp[(4 * k4 + 3) * 64];
    const int q0 = qtabi(f0, isx, Bs);
    const int q1 = qtabi(f1, isx, Bs);
    const int q2 = qtabi(f2, isx, Bs);
    const int q3 = qtabi(f3, isx, Bs);
    xp[k4 * 64] = (unsigned int)(q0 & 255) | ((unsigned int)(q1 & 255) << 8) |
                  ((unsigned int)(q2 & 255) << 16) | ((unsigned int)(q3 & 255) << 24);
  }

  // ---- phase 1: 10 j-tiles x 10 outputs ----
  float m = 0.0f;
  for (int jt = 0; jt < 10; ++jt) {
    const int j0 = jt * 10;
#define DECLA(i) float4 A##i = {0.0f, 0.0f, 0.0f, 0.0f};
    FOR10(DECLA)
#undef DECLA
    for (int k4 = 0; k4 < 25; ++k4) {
      const unsigned int p = xp[k4 * 64];
      const float x0 = (float)(((int)(p << 24)) >> 24) * sx;   // == rr*sx (exact)
      const float x1 = (float)(((int)(p << 16)) >> 24) * sx;
      const float x2 = (float)(((int)(p << 8)) >> 24) * sx;
      const float x3 = (float)(((int)p) >> 24) * sx;
      const float* wk = wq + k4 * 4;
#define FMAA(i) {                                      \
      const float* wr = wk + (j0 + i) * WSTRIDE;       \
      A##i.x = fmaf(x0, wr[0], A##i.x);                \
      A##i.y = fmaf(x1, wr[1], A##i.y);                \
      A##i.z = fmaf(x2, wr[2], A##i.z);                \
      A##i.w = fmaf(x3, wr[3], A##i.w); }
      FOR10(FMAA)
#undef FMAA
    }
#define STA(i) {                                                            \
      const float pre = ((A##i.x + A##i.y) + (A##i.z + A##i.w)) + bq[j0 + i]; \
      m = fmaxf(m, fabsf(pre));                                             \
      rp[(j0 + i) * 64] = pre; }
    FOR10(STA)
#undef STA
  }

  red[threadIdx.x] = m;
  __syncthreads();
  for (int s = 128; s > 0; s >>= 1) {
    if (threadIdx.x < s) red[threadIdx.x] = fmaxf(red[threadIdx.x], red[threadIdx.x + s]);
    __syncthreads();
  }
  if (threadIdx.x == 0) atomicMax(maxpre, __float_as_int(red[0]));
}

// ---------------- output layer ---------------------------------------------
__global__ __launch_bounds__(256) void layer_out_kernel(
    const float* __restrict__ buf, const float* __restrict__ wo0, const float* __restrict__ wo1,
    const float* __restrict__ bq32, const float* __restrict__ sxp,
    const float* __restrict__ Btab, float* __restrict__ out) {
  __shared__ float Bs[256];
  Bs[threadIdx.x] = Btab[threadIdx.x];
  __syncthreads();
  const float sx = sxp[0];
  const float isx = 1.0f / sx;
  const int row = blockIdx.x * blockDim.x + threadIdx.x;
  const float* rp = buf + buf_base(row);
  float a00 = 0.0f, a01 = 0.0f, a02 = 0.0f, a03 = 0.0f;
  float a10 = 0.0f, a11 = 0.0f, a12 = 0.0f, a13 = 0.0f;
  for (int k4 = 0; k4 < 25; ++k4) {
    const int k = k4 * 4;
    const float x0 = qtab(rp[(k + 0) * 64], sx, isx, Bs);
    const float x1 = qtab(rp[(k + 1) * 64], sx, isx, Bs);
    const float x2 = qtab(rp[(k + 2) * 64], sx, isx, Bs);
    const float x3 = qtab(rp[(k + 3) * 64], sx, isx, Bs);
    a00 = fmaf(x0, wo0[k + 0], a00); a10 = fmaf(x0, wo1[k + 0], a10);
    a01 = fmaf(x1, wo0[k + 1], a01); a11 = fmaf(x1, wo1[k + 1], a11);
    a02 = fmaf(x2, wo0[k + 2], a02); a12 = fmaf(x2, wo1[k + 2], a12);
    a03 = fmaf(x3, wo0[k + 3], a03); a13 = fmaf(x3, wo1[k + 3], a13);
  }
  float2 o;
  o.x = ((a00 + a01) + (a02 + a03)) + bq32[7 * KPAD + 0];
  o.y = ((a10 + a11) + (a12 + a13)) + bq32[7 * KPAD + 1];
  *(float2*)(out + (size_t)row * 2) = o;
}

extern "C" void kernel_launch(void* const* d_in, const int* in_sizes, int n_in,
                              void* d_out, int out_size, void* d_ws, size_t ws_size,
                              hipStream_t stream) {
  const float* z = (const float*)d_in[0];
  const float* t = (const float*)d_in[1];
  const float* Wp[8];
  const float* Bp[8];
  for (int l = 1; l <= 7; ++l) {
    Wp[l] = (const float*)d_in[2 * l];
    Bp[l] = (const float*)d_in[2 * l + 1];
  }

  char* ws = (char*)d_ws;
  size_t off = 0;
  float* buf = (float*)(ws + off);    off += (size_t)N_PTS * HID * sizeof(float);       // 105 MB
  unsigned int* xpq = (unsigned int*)(ws + off); off += (size_t)N_PTS * 25 * 4;          // 26 MB
  float* wq32 = (float*)(ws + off);   off += (size_t)5 * HID * WSTRIDE * sizeof(float);  // 224 KB
  float* w1c0 = (float*)(ws + off);   off += 128 * sizeof(float);
  float* w1c1 = (float*)(ws + off);   off += 128 * sizeof(float);
  float* wo0 = (float*)(ws + off);    off += 128 * sizeof(float);
  float* wo1 = (float*)(ws + off);    off += 128 * sizeof(float);
  float* bq32 = (float*)(ws + off);   off += 8 * KPAD * sizeof(float);
  float* Bt = (float*)(ws + off);     off += 8 * 256 * sizeof(float);
  float* swv = (float*)(ws + off);    off += 16 * sizeof(float);
  float* sxv = (float*)(ws + off);    off += 16 * sizeof(float);
  int* maxpre = (int*)(ws + off);     off += 16 * sizeof(int);  // 0xAA poison negative: atomicMax-safe
  int* inbits = (int*)(ws + off);     off += 16 * sizeof(int);
  (void)ws_size; (void)in_sizes; (void)n_in; (void)out_size;

  inmax_kernel<<<512, 256, 0, stream>>>(z, t, inbits);
  prep_kernel<<<7, 256, 0, stream>>>(Wp[1], Wp[2], Wp[3], Wp[4], Wp[5], Wp[6], Wp[7],
                                     wq32, w1c0, w1c1, wo0, wo1, swv);
  scale_kernel<<<1, 256, 0, stream>>>(0, Bp[1], HID, swv, sxv, bq32, Bt, maxpre, inbits);
  layer1_kernel<<<N_PTS / 256, 256, 0, stream>>>(z, t, w1c0, w1c1, bq32, sxv, buf, maxpre + 1);
  for (int l = 2; l <= 6; ++l) {
    scale_kernel<<<1, 256, 0, stream>>>(l - 1, Bp[l], HID, swv, sxv, bq32, Bt, maxpre, inbits);
    layer_mid_kernel<<<N_PTS / 256, 256, 0, stream>>>(buf, xpq,
                                                      wq32 + (size_t)(l - 2) * HID * WSTRIDE,
                                                      bq32 + l * KPAD, sxv + (l - 1),
                                                      Bt + (l - 1) * 256, maxpre + l);
  }
  scale_kernel<<<1, 256, 0, stream>>>(6, Bp[7], 2, swv, sxv, bq32, Bt, maxpre, inbits);
  layer_out_kernel<<<N_PTS / 256, 256, 0, stream>>>(buf, wo0, wo1, bq32, sxv + 6,
                                                    Bt + 6 * 256, (float*)d_out);
}